// Round 1
// baseline (474.865 us; speedup 1.0000x reference)
//
#include <hip/hip_runtime.h>

typedef float f32x4 __attribute__((ext_vector_type(4)));
typedef __bf16 bf16x8 __attribute__((ext_vector_type(8)));
typedef unsigned short u16;

// Problem constants
// U=4000 P=4000 G=200 B=512 D=64, LAYERS=1
// train adj: 8000x8000, g_u/g_p adj: 4200x4200 (Kpad 4224 = 132 ksteps of 32)

// ---- workspace layout (byte offsets, all 16B aligned) ----
constexpr size_t OFF_XTT = 0;                                   // xT train bf16 [64][8000]
constexpr size_t OFF_XGU = OFF_XTT + (size_t)64 * 8000 * 2;     // xT g_u bf16 [64][4224]
constexpr size_t OFF_XGP = OFF_XGU + (size_t)64 * 4224 * 2;     // xT g_p bf16 [64][4224]
constexpr size_t OFF_P0  = OFF_XGP + (size_t)64 * 4224 * 2;     // partial job0 [4][512][64] f32
constexpr size_t OFF_P1  = OFF_P0 + (size_t)4 * 512 * 64 * 4;   // partial job1 [4][4000][64]
constexpr size_t OFF_P2  = OFF_P1 + (size_t)4 * 4000 * 64 * 4;  // partial job2 [3][512][64]
constexpr size_t OFF_P3  = OFF_P2 + (size_t)3 * 512 * 64 * 4;   // partial job3 [3][4000][64]
constexpr size_t OFF_D0  = OFF_P3 + (size_t)3 * 4000 * 64 * 4;  // deg partial [4][512]
constexpr size_t OFF_D1  = OFF_D0 + (size_t)4 * 512 * 4;        // [4][4000]
constexpr size_t OFF_D2  = OFF_D1 + (size_t)4 * 4000 * 4;       // [3][512]
constexpr size_t OFF_D3  = OFF_D2 + (size_t)3 * 512 * 4;        // [3][4000]
constexpr size_t OFF_UPU = OFF_D3 + (size_t)3 * 4000 * 4;       // u_p user rows (sel) f32 [512][64]
constexpr size_t OFF_GUU = OFF_UPU + (size_t)512 * 64 * 4;      // g_u user rows (sel) f32 [512][64]
constexpr size_t OFF_UPB = OFF_GUU + (size_t)512 * 64 * 4;      // u_p paper rows bf16 [4000][64]
constexpr size_t OFF_GPB = OFF_UPB + (size_t)4000 * 64 * 2;     // g_p paper rows bf16 [4000][64]
constexpr size_t OFF_UFB = OFF_GPB + (size_t)4000 * 64 * 2;     // user_feat bf16 [512][64]
constexpr size_t OFF_QB  = OFF_UFB + (size_t)512 * 64 * 2;      // q*0.125 bf16 [512][64]

static __device__ __forceinline__ u16 f2bf(float f) {
    union { float f; unsigned u; } v; v.f = f;
    unsigned r = v.u + 0x7FFFu + ((v.u >> 16) & 1u);   // RNE
    return (u16)(r >> 16);
}

// ---------------------------------------------------------------------------
// K0: build bf16 transposed feature matrices xT[n][k] for the three jobs
// ---------------------------------------------------------------------------
__global__ __launch_bounds__(256) void build_xT(const float* __restrict__ ue,
                                                const float* __restrict__ pe,
                                                const float* __restrict__ ge,
                                                char* __restrict__ ws) {
    __shared__ float tile[64 * 65];
    int wg = blockIdx.x, tid = threadIdx.x;
    int t, kt;
    if (wg < 125)      { t = 0; kt = wg; }
    else if (wg < 191) { t = 1; kt = wg - 125; }
    else               { t = 2; kt = wg - 191; }
    int k0 = kt * 64;
#pragma unroll
    for (int rep = 0; rep < 16; ++rep) {
        int e = rep * 256 + tid;
        int r = e >> 6, c = e & 63;
        int k = k0 + r;
        float v;
        if (t == 0)      v = (k < 4000) ? ue[(size_t)k * 64 + c] : pe[(size_t)(k - 4000) * 64 + c];
        else if (t == 1) v = (k < 200) ? ge[(size_t)k * 64 + c] : ((k < 4200) ? ue[(size_t)(k - 200) * 64 + c] : 0.0f);
        else             v = (k < 200) ? ge[(size_t)k * 64 + c] : ((k < 4200) ? pe[(size_t)(k - 200) * 64 + c] : 0.0f);
        tile[r * 65 + c] = v;
    }
    __syncthreads();
    u16* dst; int Kpad;
    if (t == 0)      { dst = (u16*)(ws + OFF_XTT); Kpad = 8000; }
    else if (t == 1) { dst = (u16*)(ws + OFF_XGU); Kpad = 4224; }
    else             { dst = (u16*)(ws + OFF_XGP); Kpad = 4224; }
#pragma unroll
    for (int rep = 0; rep < 16; ++rep) {
        int e = rep * 256 + tid;
        int n = e >> 6, kk = e & 63;
        dst[(size_t)n * Kpad + k0 + kk] = f2bf(tile[kk * 65 + n]);
    }
}

// ---------------------------------------------------------------------------
// P: fused rowsum + (adj @ x) MFMA GEMM over only the needed rows, K-split.
// Wave = 16 rows x 64 cols x one K-chunk. Work items:
//  job0: train rows user_ids        32 rowtiles x 4 chunks = 128    [0,128)
//  job1: train rows 4000..7999     250 rowtiles x 4 chunks = 1000   [128,1128)
//  job2: g_u rows 200+user_ids      32 x 3 = 96                     [1128,1224)
//  job3: g_p rows 200..4199        250 x 3 = 750                    [1224,1974)
// ---------------------------------------------------------------------------
__global__ __launch_bounds__(256) void prop_kernel(const float* __restrict__ adjT,
                                                   const float* __restrict__ adjGU,
                                                   const float* __restrict__ adjGP,
                                                   const int* __restrict__ uids,
                                                   char* __restrict__ ws) {
    int wid = blockIdx.x * 4 + (threadIdx.x >> 6);
    if (wid >= 1974) return;
    int lane = threadIdx.x & 63;
    int m = lane & 15, quad = lane >> 4;

    int job, rowtile, chunk;
    if (wid < 128)       { job = 0; rowtile = wid >> 2; chunk = wid & 3; }
    else if (wid < 1128) { int t = wid - 128;  job = 1; rowtile = t >> 2; chunk = t & 3; }
    else if (wid < 1224) { int t = wid - 1128; job = 2; rowtile = t / 3; chunk = t - rowtile * 3; }
    else                 { int t = wid - 1224; job = 3; rowtile = t / 3; chunk = t - rowtile * 3; }

    const float* adj; const u16* xT; float* part; float* degp;
    int adjK, Kpad, sb, se, rowg;
    int row_local = rowtile * 16 + m;
    if (job <= 1) {
        adj = adjT; adjK = 8000; Kpad = 8000; xT = (const u16*)(ws + OFF_XTT);
        sb = chunk * 63; se = (sb + 63 < 250) ? sb + 63 : 250;
        if (job == 0) {
            rowg = uids[row_local];
            part = (float*)(ws + OFF_P0) + ((size_t)chunk * 512 + rowtile * 16) * 64;
            degp = (float*)(ws + OFF_D0) + chunk * 512 + rowtile * 16;
        } else {
            rowg = 4000 + row_local;
            part = (float*)(ws + OFF_P1) + ((size_t)chunk * 4000 + rowtile * 16) * 64;
            degp = (float*)(ws + OFF_D1) + chunk * 4000 + rowtile * 16;
        }
    } else {
        adjK = 4200; Kpad = 4224;
        sb = chunk * 44; se = sb + 44;
        if (job == 2) {
            adj = adjGU; xT = (const u16*)(ws + OFF_XGU);
            rowg = 200 + uids[row_local];
            part = (float*)(ws + OFF_P2) + ((size_t)chunk * 512 + rowtile * 16) * 64;
            degp = (float*)(ws + OFF_D2) + chunk * 512 + rowtile * 16;
        } else {
            adj = adjGP; xT = (const u16*)(ws + OFF_XGP);
            rowg = 200 + row_local;
            part = (float*)(ws + OFF_P3) + ((size_t)chunk * 4000 + rowtile * 16) * 64;
            degp = (float*)(ws + OFF_D3) + chunk * 4000 + rowtile * 16;
        }
    }

    const float* arow = adj + (size_t)rowg * adjK;
    const u16* xb0 = xT + (size_t)m * Kpad + quad * 8;
    const size_t bstride = (size_t)16 * Kpad;

    f32x4 acc[4];
#pragma unroll
    for (int nt = 0; nt < 4; ++nt) acc[nt] = (f32x4){0.f, 0.f, 0.f, 0.f};
    float degsum = 0.f;

#pragma unroll 2
    for (int s = sb; s < se; ++s) {
        int k0 = s * 32 + quad * 8;
        float a[8];
        if (k0 + 8 <= adjK) {
            f32x4 v0 = __builtin_nontemporal_load((const f32x4*)(arow + k0));
            f32x4 v1 = __builtin_nontemporal_load((const f32x4*)(arow + k0 + 4));
            a[0] = v0[0]; a[1] = v0[1]; a[2] = v0[2]; a[3] = v0[3];
            a[4] = v1[0]; a[5] = v1[1]; a[6] = v1[2]; a[7] = v1[3];
        } else {
#pragma unroll
            for (int j = 0; j < 8; ++j) a[j] = (k0 + j < adjK) ? arow[k0 + j] : 0.0f;
        }
        degsum += ((a[0] + a[1]) + (a[2] + a[3])) + ((a[4] + a[5]) + (a[6] + a[7]));
        union { u16 h[8]; bf16x8 v; } af;
#pragma unroll
        for (int j = 0; j < 8; ++j) af.h[j] = f2bf(a[j]);
        const u16* bp = xb0 + s * 32;
#pragma unroll
        for (int nt = 0; nt < 4; ++nt) {
            bf16x8 bf = *(const bf16x8*)(bp + nt * bstride);
            acc[nt] = __builtin_amdgcn_mfma_f32_16x16x32_bf16(af.v, bf, acc[nt], 0, 0, 0);
        }
    }

    // reduce deg across the 4 k-quads holding the same row
    degsum += __shfl_xor(degsum, 16, 64);
    degsum += __shfl_xor(degsum, 32, 64);
    if (lane < 16) degp[lane] = degsum;

#pragma unroll
    for (int nt = 0; nt < 4; ++nt)
#pragma unroll
        for (int r = 0; r < 4; ++r)
            part[(size_t)(quad * 4 + r) * 64 + nt * 16 + m] = acc[nt][r];
}

// ---------------------------------------------------------------------------
// E1: reduce K-chunk partials, finalize propagate rows:
//     res = 0.5*(x[row] + dot/max(deg,1e-8))
// ---------------------------------------------------------------------------
__global__ __launch_bounds__(256) void epi1(const float* __restrict__ ue,
                                            const float* __restrict__ pe,
                                            const int* __restrict__ uids,
                                            char* __restrict__ ws) {
    int e = blockIdx.x * 256 + threadIdx.x;
    if (e >= 9024 * 64) return;
    int row = e >> 6, c = e & 63;
    const float* part; const float* degp; const float* xsrc;
    int nch, r, nrows;
    float* outf = nullptr; u16* outh = nullptr;
    if (row < 512) {
        r = row; nch = 4; nrows = 512;
        part = (const float*)(ws + OFF_P0); degp = (const float*)(ws + OFF_D0);
        xsrc = ue + (size_t)uids[r] * 64;
        outf = (float*)(ws + OFF_UPU) + (size_t)r * 64;
    } else if (row < 4512) {
        r = row - 512; nch = 4; nrows = 4000;
        part = (const float*)(ws + OFF_P1); degp = (const float*)(ws + OFF_D1);
        xsrc = pe + (size_t)r * 64;
        outh = (u16*)(ws + OFF_UPB) + (size_t)r * 64;
    } else if (row < 5024) {
        r = row - 4512; nch = 3; nrows = 512;
        part = (const float*)(ws + OFF_P2); degp = (const float*)(ws + OFF_D2);
        xsrc = ue + (size_t)uids[r] * 64;
        outf = (float*)(ws + OFF_GUU) + (size_t)r * 64;
    } else {
        r = row - 5024; nch = 3; nrows = 4000;
        part = (const float*)(ws + OFF_P3); degp = (const float*)(ws + OFF_D3);
        xsrc = pe + (size_t)r * 64;
        outh = (u16*)(ws + OFF_GPB) + (size_t)r * 64;
    }
    float dot = 0.f, deg = 0.f;
    for (int cc = 0; cc < nch; ++cc) {
        dot += part[((size_t)cc * nrows + r) * 64 + c];
        deg += degp[(size_t)cc * nrows + r];
    }
    float res = 0.5f * (xsrc[c] + dot / fmaxf(deg, 1e-8f));
    if (outf) outf[c] = res; else outh[c] = f2bf(res);
}

// ---------------------------------------------------------------------------
// E2: user_feat = 0.5*(upu+guu) -> d_out tail + bf16; q = (uf @ W)*0.125 -> bf16
// ---------------------------------------------------------------------------
__global__ __launch_bounds__(256) void epi2(const float* __restrict__ W,
                                            float* __restrict__ dout,
                                            char* __restrict__ ws) {
    int e = blockIdx.x * 256 + threadIdx.x;   // < 512*64
    int b = e >> 6, n = e & 63;
    const float* upu = (const float*)(ws + OFF_UPU);
    const float* guu = (const float*)(ws + OFF_GUU);
    float uf = 0.5f * (upu[(size_t)b * 64 + n] + guu[(size_t)b * 64 + n]);
    dout[(size_t)512 * 4000 + e] = uf;
    ((u16*)(ws + OFF_UFB))[e] = f2bf(uf);
    float q = 0.f;
#pragma unroll 8
    for (int d = 0; d < 64; ++d)
        q += 0.5f * (upu[(size_t)b * 64 + d] + guu[(size_t)b * 64 + d]) * W[d * 64 + n];
    ((u16*)(ws + OFF_QB))[e] = f2bf(q * 0.125f);
}

// ---------------------------------------------------------------------------
// K3: fused attention scoring. Wave = 16 b x 16 p tile; 4 MFMA dots (K=64),
// per-element 2-way softmax epilogue, scores -> d_out.
// ---------------------------------------------------------------------------
__global__ __launch_bounds__(256) void attn(char* __restrict__ ws,
                                            float* __restrict__ dout) {
    int wid = blockIdx.x * 4 + (threadIdx.x >> 6);   // < 8000 = 32 btiles * 250 ptiles
    if (wid >= 8000) return;
    int lane = threadIdx.x & 63, m = lane & 15, quad = lane >> 4;
    int btile = wid / 250, ptile = wid - btile * 250;

    const u16* qr = (const u16*)(ws + OFF_QB)  + ((size_t)btile * 16 + m) * 64 + quad * 8;
    const u16* ur = (const u16*)(ws + OFF_UFB) + ((size_t)btile * 16 + m) * 64 + quad * 8;
    const u16* pr = (const u16*)(ws + OFF_UPB) + ((size_t)ptile * 16 + m) * 64 + quad * 8;
    const u16* gr = (const u16*)(ws + OFF_GPB) + ((size_t)ptile * 16 + m) * 64 + quad * 8;

    f32x4 s1 = (f32x4){0.f,0.f,0.f,0.f}, s2 = s1, d1 = s1, d2 = s1;
#pragma unroll
    for (int ks = 0; ks < 2; ++ks) {
        bf16x8 qf  = *(const bf16x8*)(qr + ks * 32);
        bf16x8 uff = *(const bf16x8*)(ur + ks * 32);
        bf16x8 upf = *(const bf16x8*)(pr + ks * 32);
        bf16x8 gpf = *(const bf16x8*)(gr + ks * 32);
        s1 = __builtin_amdgcn_mfma_f32_16x16x32_bf16(qf,  upf, s1, 0, 0, 0);
        s2 = __builtin_amdgcn_mfma_f32_16x16x32_bf16(qf,  gpf, s2, 0, 0, 0);
        d1 = __builtin_amdgcn_mfma_f32_16x16x32_bf16(uff, upf, d1, 0, 0, 0);
        d2 = __builtin_amdgcn_mfma_f32_16x16x32_bf16(uff, gpf, d2, 0, 0, 0);
    }
#pragma unroll
    for (int r = 0; r < 4; ++r) {
        int b = btile * 16 + quad * 4 + r;
        int p = ptile * 16 + m;
        float l0 = s1[r], l1 = s2[r];
        float mx = fmaxf(l0, l1);
        float e0 = __expf(l0 - mx), e1 = __expf(l1 - mx);
        dout[(size_t)b * 4000 + p] = (e0 * d1[r] + e1 * d2[r]) / (e0 + e1);
    }
}

extern "C" void kernel_launch(void* const* d_in, const int* in_sizes, int n_in,
                              void* d_out, int out_size, void* d_ws, size_t ws_size,
                              hipStream_t stream) {
    const float* adjT  = (const float*)d_in[0];
    const float* adjGU = (const float*)d_in[1];
    const float* adjGP = (const float*)d_in[2];
    const float* ue    = (const float*)d_in[3];
    const float* pe    = (const float*)d_in[4];
    const float* ge    = (const float*)d_in[5];
    const float* W     = (const float*)d_in[6];
    const int*   uids  = (const int*)d_in[7];
    char* ws = (char*)d_ws;
    float* dout = (float*)d_out;

    hipLaunchKernelGGL(build_xT, dim3(257), dim3(256), 0, stream, ue, pe, ge, ws);
    hipLaunchKernelGGL(prop_kernel, dim3(494), dim3(256), 0, stream, adjT, adjGU, adjGP, uids, ws);
    hipLaunchKernelGGL(epi1, dim3((9024 * 64) / 256), dim3(256), 0, stream, ue, pe, uids, ws);
    hipLaunchKernelGGL(epi2, dim3(128), dim3(256), 0, stream, W, dout, ws);
    hipLaunchKernelGGL(attn, dim3(2000), dim3(256), 0, stream, ws, dout);
}